// Round 10
// baseline (8490.196 us; speedup 1.0000x reference)
//
#include <hip/hip_runtime.h>
#include <math.h>

#define B_ 8
#define CIN_ 128
#define COUT_ 256
#define N_ 8192
#define M_ 2048
#define K_ 16

// ---------------------------------------------------------------------------
// FPS: one block per batch, 512 threads x 16 pts. fp32 decision math with
// EXPLICIT FMA chains (XLA:CPU-style contraction):
//   d = fmaf(dz,dz, fmaf(dy,dy, dx*dx))
// Two-barrier reduction, thread-0 serial finish, index tie-break (smaller).
// ---------------------------------------------------------------------------
__global__ __launch_bounds__(512) void fps_kernel(const float* __restrict__ coords,
                                                  float* __restrict__ fpts,
                                                  float* __restrict__ out_fps) {
#pragma clang fp contract(off)
    const int b = blockIdx.x;
    const int tid = threadIdx.x;
    const int lane = tid & 63;
    const int wid = tid >> 6;                    // 0..7
    const float* cb = coords + (size_t)b * 3 * N_;

    float px[16], py[16], pz[16], mind[16];
#pragma unroll
    for (int s = 0; s < 16; ++s) {
        int p = tid + s * 512;
        px[s] = cb[p];
        py[s] = cb[N_ + p];
        pz[s] = cb[2 * N_ + p];
        mind[s] = 1e10f;
    }
    float lx = cb[0], ly = cb[N_], lz = cb[2 * N_];

    __shared__ float rv[8], rx[8], ry[8], rz[8];
    __shared__ int   ri[8];
    __shared__ float bcx, bcy, bcz;

    if (tid == 0) {
        ((float4*)fpts)[b * M_ + 0] = make_float4(lx, ly, lz, 0.f);
        out_fps[(size_t)b * 3 * M_ + 0 * M_ + 0] = lx;
        out_fps[(size_t)b * 3 * M_ + 1 * M_ + 0] = ly;
        out_fps[(size_t)b * 3 * M_ + 2 * M_ + 0] = lz;
    }

    for (int m = 1; m < M_; ++m) {
        float bv = -1.0f; int bi = 0x7fffffff;
        float bx = 0.f, by = 0.f, bz = 0.f;
#pragma unroll
        for (int s = 0; s < 16; ++s) {
            float dx = px[s] - lx;
            float dy = py[s] - ly;
            float dz = pz[s] - lz;
            float d = __builtin_fmaf(dz, dz, __builtin_fmaf(dy, dy, dx * dx));  // FMA chain
            float mn = fminf(mind[s], d);
            mind[s] = mn;
            int idx = tid + s * 512;
            if (mn > bv || (mn == bv && idx < bi)) {
                bv = mn; bi = idx; bx = px[s]; by = py[s]; bz = pz[s];
            }
        }
#pragma unroll
        for (int off = 1; off < 64; off <<= 1) {
            float ov = __shfl_xor(bv, off);
            int   oi = __shfl_xor(bi, off);
            float ox = __shfl_xor(bx, off);
            float oy = __shfl_xor(by, off);
            float oz = __shfl_xor(bz, off);
            if (ov > bv || (ov == bv && oi < bi)) { bv = ov; bi = oi; bx = ox; by = oy; bz = oz; }
        }
        if (lane == 0) { rv[wid] = bv; ri[wid] = bi; rx[wid] = bx; ry[wid] = by; rz[wid] = bz; }
        __syncthreads();
        if (tid == 0) {
            float v = rv[0]; int i = ri[0];
            float X = rx[0], Y = ry[0], Z = rz[0];
            for (int w = 1; w < 8; ++w)
                if (rv[w] > v || (rv[w] == v && ri[w] < i)) { v = rv[w]; i = ri[w]; X = rx[w]; Y = ry[w]; Z = rz[w]; }
            bcx = X; bcy = Y; bcz = Z;
            ((float4*)fpts)[b * M_ + m] = make_float4(X, Y, Z, 0.f);
            out_fps[(size_t)b * 3 * M_ + 0 * M_ + m] = X;
            out_fps[(size_t)b * 3 * M_ + 1 * M_ + m] = Y;
            out_fps[(size_t)b * 3 * M_ + 2 * M_ + m] = Z;
        }
        __syncthreads();
        lx = bcx; ly = bcy; lz = bcz;
    }
}

// ---------------------------------------------------------------------------
// kNN: one thread per (b,m) row; fp32 FMA-chain distances:
//   sf/sp = fmaf(z,z,fmaf(y,y,x*x)),  dot = fmaf(fz,gz,fmaf(fy,gy,fx*gx)),
//   d = (sf + sp) - 2*dot.   Top-16 replace-worst under lex (d, idx).
// ---------------------------------------------------------------------------
__global__ __launch_bounds__(128) void knn_kernel(const float* __restrict__ coords,
                                                  const float* __restrict__ fpts,
                                                  int* __restrict__ knn) {
#pragma clang fp contract(off)
    const int row = blockIdx.x * 128 + threadIdx.x;   // 0..16383
    const int b = row >> 11;
    const float* cb = coords + (size_t)b * 3 * N_;

    float4 f = ((const float4*)fpts)[row];
    const float fx = f.x, fy = f.y, fz = f.z;
    const float sf = __builtin_fmaf(fz, fz, __builtin_fmaf(fy, fy, fx * fx));

    float nd[K_]; int ni[K_];
#pragma unroll
    for (int j = 0; j < K_; ++j) { nd[j] = 1e30f; ni[j] = 0x7fffffff; }
    float wd = 1e30f; int wi = 0x7fffffff; int wslot = 0;

    for (int n = 0; n < N_; ++n) {
        float gx = cb[n], gy = cb[N_ + n], gz = cb[2 * N_ + n];
        float sp = __builtin_fmaf(gz, gz, __builtin_fmaf(gy, gy, gx * gx));
        float dot = __builtin_fmaf(fz, gz, __builtin_fmaf(fy, gy, fx * gx));
        float d = (sf + sp) - 2.0f * dot;
        if (d < wd || (d == wd && n < wi)) {
#pragma unroll
            for (int j = 0; j < K_; ++j) if (j == wslot) { nd[j] = d; ni[j] = n; }
            wd = nd[0]; wi = ni[0]; wslot = 0;
#pragma unroll
            for (int j = 1; j < K_; ++j)
                if (nd[j] > wd || (nd[j] == wd && ni[j] > wi)) { wd = nd[j]; wi = ni[j]; wslot = j; }
        }
    }
#pragma unroll
    for (int j = 0; j < K_; ++j) {
        int v = ni[j];
        knn[row * K_ + j] = ((unsigned)v < (unsigned)N_) ? v : 0;   // fault guard
    }
}

// ---------------------------------------------------------------------------
// Per-point GEMM: hp[b][n][o] = sum_c x[b][c][n] * W[o][c]  (f32 acc, LDS tile)
// ---------------------------------------------------------------------------
__global__ __launch_bounds__(256) void gemm_kernel(const float* __restrict__ x,
                                                   const float* __restrict__ W,
                                                   float* __restrict__ hp) {
    const int bid = blockIdx.x;
    const int b = bid >> 9;
    const int rem = bid & 511;
    const int n0 = (rem >> 2) * 64;
    const int o0 = (rem & 3) * 64;
    const int tid = threadIdx.x;
    const int tn = (tid & 15) * 4;
    const int to = (tid >> 4) * 4;
    const float* xg = x + (size_t)b * CIN_ * N_;

    __shared__ float Xs[64][64];
    __shared__ float Wt[64][68];

    float acc[4][4] = {};
    for (int kk = 0; kk < CIN_; kk += 64) {
#pragma unroll
        for (int i = 0; i < 16; ++i) {
            int e = tid + 256 * i;
            int r = e >> 6, q = e & 63;
            Xs[r][q] = xg[(size_t)(kk + r) * N_ + n0 + q];
            Wt[q][r] = W[(size_t)(o0 + r) * CIN_ + kk + q];
        }
        __syncthreads();
#pragma unroll 8
        for (int c = 0; c < 64; ++c) {
            float4 a = *(const float4*)&Xs[c][tn];
            float4 bb = *(const float4*)&Wt[c][to];
            float av[4] = {a.x, a.y, a.z, a.w};
            float bv[4] = {bb.x, bb.y, bb.z, bb.w};
#pragma unroll
            for (int j = 0; j < 4; ++j)
#pragma unroll
                for (int l = 0; l < 4; ++l)
                    acc[j][l] += av[j] * bv[l];
        }
        __syncthreads();
    }
#pragma unroll
    for (int j = 0; j < 4; ++j) {
        float4 v = make_float4(acc[j][0], acc[j][1], acc[j][2], acc[j][3]);
        *(float4*)&hp[((size_t)b * N_ + n0 + tn + j) * COUT_ + o0 + to] = v;
    }
}

// ---------------------------------------------------------------------------
// BN stats stage 1: deterministic per-block f64 partials (no atomics).
// ---------------------------------------------------------------------------
__global__ __launch_bounds__(256) void stats_partial_kernel(const float* __restrict__ hp,
                                                            const int* __restrict__ knn,
                                                            double* __restrict__ partial,
                                                            double* __restrict__ partial2) {
    const int o = threadIdx.x;
    const int g0 = blockIdx.x * 1024;              // 262144 gathered rows total
    double s = 0.0, s2 = 0.0;
    for (int r = 0; r < 1024; ++r) {
        int g = g0 + r;                            // g = (b*M + m)*K + k
        int row = g >> 4;
        int k = g & 15;
        int b = row >> 11;
        int n = knn[row * K_ + k];
        n = ((unsigned)n < (unsigned)N_) ? n : 0;  // fault guard
        double h = (double)hp[((size_t)b * N_ + n) * COUT_ + o];
        s += h;
        s2 += h * h;
    }
    partial[(size_t)blockIdx.x * 256 + o] = s;
    partial2[(size_t)blockIdx.x * 256 + o] = s2;
}

__global__ void bn_final_kernel(const double* __restrict__ partial,
                                const double* __restrict__ partial2,
                                const float* __restrict__ gamma,
                                const float* __restrict__ beta,
                                float* __restrict__ scale,
                                float* __restrict__ bias) {
    int o = threadIdx.x;
    double s = 0.0, s2 = 0.0;
    for (int j = 0; j < 256; ++j) {
        s += partial[(size_t)j * 256 + o];
        s2 += partial2[(size_t)j * 256 + o];
    }
    const double inv = 1.0 / (double)(B_ * M_ * K_);
    double mean = s * inv;
    double var = s2 * inv - mean * mean;
    if (var < 0.0) var = 0.0;
    double r = 1.0 / sqrt(var + 1e-5);
    double g = (double)gamma[o];
    scale[o] = (float)(r * g);
    bias[o] = (float)((double)beta[o] - mean * r * g);
}

// ---------------------------------------------------------------------------
// Finalize: y[b][o][m] = relu( max_k ( hp[gather] * scale + bias ) )  (f32)
// ---------------------------------------------------------------------------
__global__ __launch_bounds__(256) void finalize_kernel(const float* __restrict__ hp,
                                                       const int* __restrict__ knn,
                                                       const float* __restrict__ scale,
                                                       const float* __restrict__ bias,
                                                       float* __restrict__ y) {
    const int b = blockIdx.x >> 6;
    const int m0 = (blockIdx.x & 63) * 32;
    const int tid = threadIdx.x;
    __shared__ int kidx[512];
    __shared__ float tile[32][257];

    for (int e = tid; e < 512; e += 256) {
        int n = knn[(b * M_ + m0 + (e >> 4)) * K_ + (e & 15)];
        kidx[e] = ((unsigned)n < (unsigned)N_) ? n : 0;   // fault guard
    }
    __syncthreads();

    const float s = scale[tid];
    const float t = bias[tid];
    const float* hb = hp + (size_t)b * N_ * COUT_;
    for (int mm = 0; mm < 32; ++mm) {
        float v = -INFINITY;
#pragma unroll
        for (int k = 0; k < K_; ++k) {
            int n = kidx[mm * 16 + k];
            float h = hb[(size_t)n * COUT_ + tid];
            v = fmaxf(v, h * s + t);
        }
        v = fmaxf(v, 0.0f);
        tile[mm][tid] = v;
    }
    __syncthreads();
#pragma unroll
    for (int r = 0; r < 32; ++r) {
        int o2 = r * 8 + (tid >> 5);
        int mm = tid & 31;
        y[((size_t)b * COUT_ + o2) * M_ + m0 + mm] = tile[mm][o2];
    }
}

__global__ void sentinel_kernel(float* out, float v) { out[0] = v; }

// ---------------------------------------------------------------------------
extern "C" void kernel_launch(void* const* d_in, const int* in_sizes, int n_in,
                              void* d_out, int out_size, void* d_ws, size_t ws_size,
                              hipStream_t stream) {
    const float* x = (const float*)d_in[0];
    const float* coords = (const float*)d_in[1];
    const float* W = (const float*)d_in[2];
    const float* gamma = (const float*)d_in[3];
    const float* beta = (const float*)d_in[4];
    float* y = (float*)d_out;
    float* out_fps = y + (size_t)B_ * COUT_ * M_;     // fps_coords after y (f32)

    if (n_in != 5 ||
        in_sizes[0] != B_ * CIN_ * N_ ||
        in_sizes[1] != B_ * 3 * N_ ||
        in_sizes[2] != COUT_ * CIN_ ||
        in_sizes[3] != COUT_ || in_sizes[4] != COUT_ ||
        out_size != B_ * COUT_ * M_ + B_ * 3 * M_) {
        sentinel_kernel<<<1, 1, 0, stream>>>(y, -2.0e6f);
        return;
    }

    const size_t HP_BYTES = (size_t)B_ * N_ * COUT_ * 4;          // 64 MB
    const size_t FPTS_BYTES = (size_t)B_ * M_ * 16;               // 256 KB
    const size_t KNN_BYTES = (size_t)B_ * M_ * K_ * 4;            // 1 MB
    const size_t PART_BYTES = (size_t)256 * 256 * 8;              // 512 KB
    const size_t NEED = HP_BYTES + FPTS_BYTES + KNN_BYTES + 2 * PART_BYTES + 8192;
    if (ws_size < NEED) {
        sentinel_kernel<<<1, 1, 0, stream>>>(y, -1.0e6f);
        return;
    }
    char* ws = (char*)d_ws;
    float* hp = (float*)ws;
    float* fpts = (float*)(ws + HP_BYTES);
    int* knn = (int*)(ws + HP_BYTES + FPTS_BYTES);
    double* partial = (double*)(ws + HP_BYTES + FPTS_BYTES + KNN_BYTES);
    double* partial2 = (double*)(ws + HP_BYTES + FPTS_BYTES + KNN_BYTES + PART_BYTES);
    float* scale = (float*)(ws + HP_BYTES + FPTS_BYTES + KNN_BYTES + 2 * PART_BYTES);
    float* bias = scale + 256;

    fps_kernel<<<B_, 512, 0, stream>>>(coords, fpts, out_fps);
    knn_kernel<<<B_ * M_ / 128, 128, 0, stream>>>(coords, fpts, knn);
    gemm_kernel<<<B_ * 512, 256, 0, stream>>>(x, W, hp);
    stats_partial_kernel<<<256, 256, 0, stream>>>(hp, knn, partial, partial2);
    bn_final_kernel<<<1, 256, 0, stream>>>(partial, partial2, gamma, beta, scale, bias);
    finalize_kernel<<<512, 256, 0, stream>>>(hp, knn, scale, bias, y);
}

// Round 11
// 4225.928 us; speedup vs baseline: 2.0091x; 2.0091x over previous
//
#include <hip/hip_runtime.h>
#include <math.h>

#define B_ 8
#define CIN_ 128
#define COUT_ 256
#define N_ 8192
#define M_ 2048
#define K_ 16

// ---------------------------------------------------------------------------
// DPP wave reductions (row_shr 1/2/4/8 + row_bcast 15/31 -> lane 63 holds
// the 64-lane reduction; readlane 63 broadcasts to SGPR). VALU-latency only —
// replaces 6x ds_swizzle chains (~120 cyc each, single-outstanding).
// ---------------------------------------------------------------------------
__device__ __forceinline__ unsigned umax2(unsigned a, unsigned b) { return a > b ? a : b; }
__device__ __forceinline__ unsigned umin2(unsigned a, unsigned b) { return a < b ? a : b; }

__device__ __forceinline__ unsigned wave_reduce_umax(unsigned v) {
    v = umax2(v, (unsigned)__builtin_amdgcn_update_dpp(0, (int)v, 0x111, 0xf, 0xf, false));
    v = umax2(v, (unsigned)__builtin_amdgcn_update_dpp(0, (int)v, 0x112, 0xf, 0xf, false));
    v = umax2(v, (unsigned)__builtin_amdgcn_update_dpp(0, (int)v, 0x114, 0xf, 0xf, false));
    v = umax2(v, (unsigned)__builtin_amdgcn_update_dpp(0, (int)v, 0x118, 0xf, 0xf, false));
    v = umax2(v, (unsigned)__builtin_amdgcn_update_dpp(0, (int)v, 0x142, 0xf, 0xf, false));
    v = umax2(v, (unsigned)__builtin_amdgcn_update_dpp(0, (int)v, 0x143, 0xf, 0xf, false));
    return (unsigned)__builtin_amdgcn_readlane((int)v, 63);
}
__device__ __forceinline__ unsigned wave_reduce_umin(unsigned v) {
    v = umin2(v, (unsigned)__builtin_amdgcn_update_dpp(-1, (int)v, 0x111, 0xf, 0xf, false));
    v = umin2(v, (unsigned)__builtin_amdgcn_update_dpp(-1, (int)v, 0x112, 0xf, 0xf, false));
    v = umin2(v, (unsigned)__builtin_amdgcn_update_dpp(-1, (int)v, 0x114, 0xf, 0xf, false));
    v = umin2(v, (unsigned)__builtin_amdgcn_update_dpp(-1, (int)v, 0x118, 0xf, 0xf, false));
    v = umin2(v, (unsigned)__builtin_amdgcn_update_dpp(-1, (int)v, 0x142, 0xf, 0xf, false));
    v = umin2(v, (unsigned)__builtin_amdgcn_update_dpp(-1, (int)v, 0x143, 0xf, 0xf, false));
    return (unsigned)__builtin_amdgcn_readlane((int)v, 63);
}

// ---------------------------------------------------------------------------
// FPS v2: one block/batch, 512 thr x 16 pts. Decision math IDENTICAL to the
// verified R10 kernel (fmaf chains, lex (max d, min idx)). Reduction rebuilt:
// DPP max(d-bits) -> masked DPP min(idx) -> 1 LDS u64/wave (parity-buffered)
// -> ONE barrier -> each thread u64-max over 8 -> winner coords via uniform
// global reload. Winner sequence is bit-identical to R10.
// ---------------------------------------------------------------------------
__global__ __launch_bounds__(512) void fps_kernel(const float* __restrict__ coords,
                                                  float* __restrict__ fpts,
                                                  float* __restrict__ out_fps) {
#pragma clang fp contract(off)
    const int b = blockIdx.x;
    const int tid = threadIdx.x;
    const int lane = tid & 63;
    const int wid = tid >> 6;                    // 0..7
    const float* cb = coords + (size_t)b * 3 * N_;

    float px[16], py[16], pz[16], mind[16];
#pragma unroll
    for (int s = 0; s < 16; ++s) {
        int p = tid + s * 512;
        px[s] = cb[p];
        py[s] = cb[N_ + p];
        pz[s] = cb[2 * N_ + p];
        mind[s] = 1e10f;
    }
    float lx = cb[0], ly = cb[N_], lz = cb[2 * N_];

    __shared__ unsigned long long kbuf[2][8];

    if (tid == 0) {
        ((float4*)fpts)[b * M_ + 0] = make_float4(lx, ly, lz, 0.f);
        out_fps[(size_t)b * 3 * M_ + 0 * M_ + 0] = lx;
        out_fps[(size_t)b * 3 * M_ + 1 * M_ + 0] = ly;
        out_fps[(size_t)b * 3 * M_ + 2 * M_ + 0] = lz;
    }

    int par = 0;
    for (int m = 1; m < M_; ++m) {
        float bv = -1.0f; int bi = 0;
#pragma unroll
        for (int s = 0; s < 16; ++s) {
            float dx = px[s] - lx;
            float dy = py[s] - ly;
            float dz = pz[s] - lz;
            float d = __builtin_fmaf(dz, dz, __builtin_fmaf(dy, dy, dx * dx));  // frozen FMA chain
            float mn = fminf(mind[s], d);
            mind[s] = mn;
            if (mn > bv) { bv = mn; bi = tid + s * 512; }  // strict > : smallest idx on tie
        }
        // wave: max d (u32 on bits, valid since d>=0), then min idx among max
        unsigned kd = __float_as_uint(bv);
        unsigned md = wave_reduce_umax(kd);
        unsigned cand = (kd == md) ? (unsigned)bi : 0xffffffffu;
        unsigned mi = wave_reduce_umin(cand);
        if (lane == 0)
            kbuf[par][wid] = ((unsigned long long)md << 32) |
                             (unsigned long long)(0xffffffffu - mi);   // u64 max == lex rule
        __syncthreads();
        unsigned long long best = kbuf[par][0];
#pragma unroll
        for (int w = 1; w < 8; ++w) {
            unsigned long long k2 = kbuf[par][w];
            if (k2 > best) best = k2;
        }
        int widx = (int)(0xffffffffu - (unsigned)(best & 0xffffffffull));
        widx = ((unsigned)widx < (unsigned)N_) ? widx : 0;             // fault guard
        lx = cb[widx]; ly = cb[N_ + widx]; lz = cb[2 * N_ + widx];     // uniform reload
        if (tid == 0) {
            ((float4*)fpts)[b * M_ + m] = make_float4(lx, ly, lz, 0.f);
            out_fps[(size_t)b * 3 * M_ + 0 * M_ + m] = lx;
            out_fps[(size_t)b * 3 * M_ + 1 * M_ + m] = ly;
            out_fps[(size_t)b * 3 * M_ + 2 * M_ + m] = lz;
        }
        par ^= 1;
    }
}

// ---------------------------------------------------------------------------
// kNN chunk pass: grid = 256 row-groups x 4 N-chunks, 64 thr (one row each).
// Each block computes the chunk-local top-16 with the verified R10 insert
// (lex (d, idx), order-independent). Chunk outputs overlay the hp region.
// ---------------------------------------------------------------------------
__global__ __launch_bounds__(64) void knn_chunk_kernel(const float* __restrict__ coords,
                                                       const float* __restrict__ fpts,
                                                       float* __restrict__ cd,
                                                       int* __restrict__ ci) {
#pragma clang fp contract(off)
    const int rg = blockIdx.x >> 2;               // 0..255
    const int c = blockIdx.x & 3;                 // N-chunk
    const int row = rg * 64 + threadIdx.x;        // 0..16383
    const int b = row >> 11;
    const float* cb = coords + (size_t)b * 3 * N_;

    float4 f = ((const float4*)fpts)[row];
    const float fx = f.x, fy = f.y, fz = f.z;
    const float sf = __builtin_fmaf(fz, fz, __builtin_fmaf(fy, fy, fx * fx));

    float nd[K_]; int ni[K_];
#pragma unroll
    for (int j = 0; j < K_; ++j) { nd[j] = 1e30f; ni[j] = 0x7fffffff; }
    float wd = 1e30f; int wi = 0x7fffffff; int wslot = 0;

    const int n0 = c * 2048, n1 = n0 + 2048;
    for (int n = n0; n < n1; ++n) {
        float gx = cb[n], gy = cb[N_ + n], gz = cb[2 * N_ + n];
        float sp = __builtin_fmaf(gz, gz, __builtin_fmaf(gy, gy, gx * gx));
        float dot = __builtin_fmaf(fz, gz, __builtin_fmaf(fy, gy, fx * gx));
        float d = (sf + sp) - 2.0f * dot;         // frozen op order
        if (d < wd || (d == wd && n < wi)) {
#pragma unroll
            for (int j = 0; j < K_; ++j) if (j == wslot) { nd[j] = d; ni[j] = n; }
            wd = nd[0]; wi = ni[0]; wslot = 0;
#pragma unroll
            for (int j = 1; j < K_; ++j)
                if (nd[j] > wd || (nd[j] == wd && ni[j] > wi)) { wd = nd[j]; wi = ni[j]; wslot = j; }
        }
    }
#pragma unroll
    for (int j = 0; j < K_; ++j) {
        cd[(size_t)row * 64 + c * 16 + j] = nd[j];
        ci[(size_t)row * 64 + c * 16 + j] = ni[j];
    }
}

// ---------------------------------------------------------------------------
// kNN merge: one thread per row; re-insert the 64 chunk candidates with the
// same lex insert (order-independent => exact global top-16).
// ---------------------------------------------------------------------------
__global__ __launch_bounds__(256) void knn_merge_kernel(const float* __restrict__ cd,
                                                        const int* __restrict__ ci,
                                                        int* __restrict__ knn) {
    const int row = blockIdx.x * 256 + threadIdx.x;   // 64 blocks
    float nd[K_]; int ni[K_];
#pragma unroll
    for (int j = 0; j < K_; ++j) { nd[j] = 1e30f; ni[j] = 0x7fffffff; }
    float wd = 1e30f; int wi = 0x7fffffff; int wslot = 0;

    for (int e = 0; e < 64; ++e) {
        float d = cd[(size_t)row * 64 + e];
        int n = ci[(size_t)row * 64 + e];
        if (d < wd || (d == wd && n < wi)) {
#pragma unroll
            for (int j = 0; j < K_; ++j) if (j == wslot) { nd[j] = d; ni[j] = n; }
            wd = nd[0]; wi = ni[0]; wslot = 0;
#pragma unroll
            for (int j = 1; j < K_; ++j)
                if (nd[j] > wd || (nd[j] == wd && ni[j] > wi)) { wd = nd[j]; wi = ni[j]; wslot = j; }
        }
    }
#pragma unroll
    for (int j = 0; j < K_; ++j) {
        int v = ni[j];
        knn[(size_t)row * K_ + j] = ((unsigned)v < (unsigned)N_) ? v : 0;   // fault guard
    }
}

// ---------------------------------------------------------------------------
// Per-point GEMM: hp[b][n][o] = sum_c x[b][c][n] * W[o][c]  (unchanged)
// ---------------------------------------------------------------------------
__global__ __launch_bounds__(256) void gemm_kernel(const float* __restrict__ x,
                                                   const float* __restrict__ W,
                                                   float* __restrict__ hp) {
    const int bid = blockIdx.x;
    const int b = bid >> 9;
    const int rem = bid & 511;
    const int n0 = (rem >> 2) * 64;
    const int o0 = (rem & 3) * 64;
    const int tid = threadIdx.x;
    const int tn = (tid & 15) * 4;
    const int to = (tid >> 4) * 4;
    const float* xg = x + (size_t)b * CIN_ * N_;

    __shared__ float Xs[64][64];
    __shared__ float Wt[64][68];

    float acc[4][4] = {};
    for (int kk = 0; kk < CIN_; kk += 64) {
#pragma unroll
        for (int i = 0; i < 16; ++i) {
            int e = tid + 256 * i;
            int r = e >> 6, q = e & 63;
            Xs[r][q] = xg[(size_t)(kk + r) * N_ + n0 + q];
            Wt[q][r] = W[(size_t)(o0 + r) * CIN_ + kk + q];
        }
        __syncthreads();
#pragma unroll 8
        for (int c = 0; c < 64; ++c) {
            float4 a = *(const float4*)&Xs[c][tn];
            float4 bb = *(const float4*)&Wt[c][to];
            float av[4] = {a.x, a.y, a.z, a.w};
            float bv[4] = {bb.x, bb.y, bb.z, bb.w};
#pragma unroll
            for (int j = 0; j < 4; ++j)
#pragma unroll
                for (int l = 0; l < 4; ++l)
                    acc[j][l] += av[j] * bv[l];
        }
        __syncthreads();
    }
#pragma unroll
    for (int j = 0; j < 4; ++j) {
        float4 v = make_float4(acc[j][0], acc[j][1], acc[j][2], acc[j][3]);
        *(float4*)&hp[((size_t)b * N_ + n0 + tn + j) * COUT_ + o0 + to] = v;
    }
}

// ---------------------------------------------------------------------------
// BN stats stage 1: deterministic per-block f64 partials (unchanged).
// ---------------------------------------------------------------------------
__global__ __launch_bounds__(256) void stats_partial_kernel(const float* __restrict__ hp,
                                                            const int* __restrict__ knn,
                                                            double* __restrict__ partial,
                                                            double* __restrict__ partial2) {
    const int o = threadIdx.x;
    const int g0 = blockIdx.x * 1024;              // 262144 gathered rows total
    double s = 0.0, s2 = 0.0;
    for (int r = 0; r < 1024; ++r) {
        int g = g0 + r;                            // g = (b*M + m)*K + k
        int row = g >> 4;
        int k = g & 15;
        int b = row >> 11;
        int n = knn[row * K_ + k];
        n = ((unsigned)n < (unsigned)N_) ? n : 0;  // fault guard
        double h = (double)hp[((size_t)b * N_ + n) * COUT_ + o];
        s += h;
        s2 += h * h;
    }
    partial[(size_t)blockIdx.x * 256 + o] = s;
    partial2[(size_t)blockIdx.x * 256 + o] = s2;
}

__global__ void bn_final_kernel(const double* __restrict__ partial,
                                const double* __restrict__ partial2,
                                const float* __restrict__ gamma,
                                const float* __restrict__ beta,
                                float* __restrict__ scale,
                                float* __restrict__ bias) {
    int o = threadIdx.x;
    double s = 0.0, s2 = 0.0;
    for (int j = 0; j < 256; ++j) {
        s += partial[(size_t)j * 256 + o];
        s2 += partial2[(size_t)j * 256 + o];
    }
    const double inv = 1.0 / (double)(B_ * M_ * K_);
    double mean = s * inv;
    double var = s2 * inv - mean * mean;
    if (var < 0.0) var = 0.0;
    double r = 1.0 / sqrt(var + 1e-5);
    double g = (double)gamma[o];
    scale[o] = (float)(r * g);
    bias[o] = (float)((double)beta[o] - mean * r * g);
}

// ---------------------------------------------------------------------------
// Finalize: y[b][o][m] = relu( max_k ( hp[gather] * scale + bias ) ) (unchanged)
// ---------------------------------------------------------------------------
__global__ __launch_bounds__(256) void finalize_kernel(const float* __restrict__ hp,
                                                       const int* __restrict__ knn,
                                                       const float* __restrict__ scale,
                                                       const float* __restrict__ bias,
                                                       float* __restrict__ y) {
    const int b = blockIdx.x >> 6;
    const int m0 = (blockIdx.x & 63) * 32;
    const int tid = threadIdx.x;
    __shared__ int kidx[512];
    __shared__ float tile[32][257];

    for (int e = tid; e < 512; e += 256) {
        int n = knn[(b * M_ + m0 + (e >> 4)) * K_ + (e & 15)];
        kidx[e] = ((unsigned)n < (unsigned)N_) ? n : 0;   // fault guard
    }
    __syncthreads();

    const float s = scale[tid];
    const float t = bias[tid];
    const float* hb = hp + (size_t)b * N_ * COUT_;
    for (int mm = 0; mm < 32; ++mm) {
        float v = -INFINITY;
#pragma unroll
        for (int k = 0; k < K_; ++k) {
            int n = kidx[mm * 16 + k];
            float h = hb[(size_t)n * COUT_ + tid];
            v = fmaxf(v, h * s + t);
        }
        v = fmaxf(v, 0.0f);
        tile[mm][tid] = v;
    }
    __syncthreads();
#pragma unroll
    for (int r = 0; r < 32; ++r) {
        int o2 = r * 8 + (tid >> 5);
        int mm = tid & 31;
        y[((size_t)b * COUT_ + o2) * M_ + m0 + mm] = tile[mm][o2];
    }
}

__global__ void sentinel_kernel(float* out, float v) { out[0] = v; }

// ---------------------------------------------------------------------------
extern "C" void kernel_launch(void* const* d_in, const int* in_sizes, int n_in,
                              void* d_out, int out_size, void* d_ws, size_t ws_size,
                              hipStream_t stream) {
    const float* x = (const float*)d_in[0];
    const float* coords = (const float*)d_in[1];
    const float* W = (const float*)d_in[2];
    const float* gamma = (const float*)d_in[3];
    const float* beta = (const float*)d_in[4];
    float* y = (float*)d_out;
    float* out_fps = y + (size_t)B_ * COUT_ * M_;     // fps_coords after y (f32)

    if (n_in != 5 ||
        in_sizes[0] != B_ * CIN_ * N_ ||
        in_sizes[1] != B_ * 3 * N_ ||
        in_sizes[2] != COUT_ * CIN_ ||
        in_sizes[3] != COUT_ || in_sizes[4] != COUT_ ||
        out_size != B_ * COUT_ * M_ + B_ * 3 * M_) {
        sentinel_kernel<<<1, 1, 0, stream>>>(y, -2.0e6f);
        return;
    }

    const size_t HP_BYTES = (size_t)B_ * N_ * COUT_ * 4;          // 64 MB
    const size_t FPTS_BYTES = (size_t)B_ * M_ * 16;               // 256 KB
    const size_t KNN_BYTES = (size_t)B_ * M_ * K_ * 4;            // 1 MB
    const size_t PART_BYTES = (size_t)256 * 256 * 8;              // 512 KB
    const size_t NEED = HP_BYTES + FPTS_BYTES + KNN_BYTES + 2 * PART_BYTES + 8192;
    if (ws_size < NEED) {
        sentinel_kernel<<<1, 1, 0, stream>>>(y, -1.0e6f);
        return;
    }
    char* ws = (char*)d_ws;
    float* hp = (float*)ws;
    float* fpts = (float*)(ws + HP_BYTES);
    int* knn = (int*)(ws + HP_BYTES + FPTS_BYTES);
    double* partial = (double*)(ws + HP_BYTES + FPTS_BYTES + KNN_BYTES);
    double* partial2 = (double*)(ws + HP_BYTES + FPTS_BYTES + KNN_BYTES + PART_BYTES);
    float* scale = (float*)(ws + HP_BYTES + FPTS_BYTES + KNN_BYTES + 2 * PART_BYTES);
    float* bias = scale + 256;

    // kNN chunk buffers overlay the hp region (hp written later by gemm):
    float* cd = (float*)ws;                         // 4 MB
    int* ci = (int*)(ws + (size_t)4 * 1024 * 1024); // 4 MB

    fps_kernel<<<B_, 512, 0, stream>>>(coords, fpts, out_fps);
    knn_chunk_kernel<<<1024, 64, 0, stream>>>(coords, fpts, cd, ci);
    knn_merge_kernel<<<64, 256, 0, stream>>>(cd, ci, knn);
    gemm_kernel<<<B_ * 512, 256, 0, stream>>>(x, W, hp);
    stats_partial_kernel<<<256, 256, 0, stream>>>(hp, knn, partial, partial2);
    bn_final_kernel<<<1, 256, 0, stream>>>(partial, partial2, gamma, beta, scale, bias);
    finalize_kernel<<<512, 256, 0, stream>>>(hp, knn, scale, bias, y);
}

// Round 12
// 2551.208 us; speedup vs baseline: 3.3279x; 1.6564x over previous
//
#include <hip/hip_runtime.h>
#include <math.h>

#define B_ 8
#define CIN_ 128
#define COUT_ 256
#define N_ 8192
#define M_ 2048
#define K_ 16

// ---------------------------------------------------------------------------
// DPP wave reductions (row_shr 1/2/4/8 + row_bcast 15/31): VALU-latency only.
// ---------------------------------------------------------------------------
__device__ __forceinline__ unsigned umax2(unsigned a, unsigned b) { return a > b ? a : b; }
__device__ __forceinline__ unsigned umin2(unsigned a, unsigned b) { return a < b ? a : b; }

__device__ __forceinline__ unsigned wave_reduce_umax(unsigned v) {
    v = umax2(v, (unsigned)__builtin_amdgcn_update_dpp(0, (int)v, 0x111, 0xf, 0xf, false));
    v = umax2(v, (unsigned)__builtin_amdgcn_update_dpp(0, (int)v, 0x112, 0xf, 0xf, false));
    v = umax2(v, (unsigned)__builtin_amdgcn_update_dpp(0, (int)v, 0x114, 0xf, 0xf, false));
    v = umax2(v, (unsigned)__builtin_amdgcn_update_dpp(0, (int)v, 0x118, 0xf, 0xf, false));
    v = umax2(v, (unsigned)__builtin_amdgcn_update_dpp(0, (int)v, 0x142, 0xf, 0xf, false));
    v = umax2(v, (unsigned)__builtin_amdgcn_update_dpp(0, (int)v, 0x143, 0xf, 0xf, false));
    return (unsigned)__builtin_amdgcn_readlane((int)v, 63);
}
__device__ __forceinline__ unsigned wave_reduce_umin(unsigned v) {
    v = umin2(v, (unsigned)__builtin_amdgcn_update_dpp(-1, (int)v, 0x111, 0xf, 0xf, false));
    v = umin2(v, (unsigned)__builtin_amdgcn_update_dpp(-1, (int)v, 0x112, 0xf, 0xf, false));
    v = umin2(v, (unsigned)__builtin_amdgcn_update_dpp(-1, (int)v, 0x114, 0xf, 0xf, false));
    v = umin2(v, (unsigned)__builtin_amdgcn_update_dpp(-1, (int)v, 0x118, 0xf, 0xf, false));
    v = umin2(v, (unsigned)__builtin_amdgcn_update_dpp(-1, (int)v, 0x142, 0xf, 0xf, false));
    v = umin2(v, (unsigned)__builtin_amdgcn_update_dpp(-1, (int)v, 0x143, 0xf, 0xf, false));
    return (unsigned)__builtin_amdgcn_readlane((int)v, 63);
}

// ---------------------------------------------------------------------------
// FPS v3: one block/batch, 1024 thr x 8 pts (registers; only 32 VGPRs of
// per-thread state so the compiler keeps them resident instead of re-loading
// from global each iteration — R11's VGPR_Count=56 showed rematerialization).
// Coords also staged to LDS float4 for the winner lookup (broadcast b128).
// NO global stores in the loop: winner indices parked in 2 regs/thread,
// written in an epilogue. Decision math FROZEN (fmaf chain, strict >, DPP
// max-d / min-idx, u64 lex key) — winner sequence bit-identical to R11.
// ---------------------------------------------------------------------------
__global__ __launch_bounds__(1024) void fps_kernel(const float* __restrict__ coords,
                                                   float* __restrict__ fpts,
                                                   float* __restrict__ out_fps) {
#pragma clang fp contract(off)
    const int b = blockIdx.x;
    const int tid = threadIdx.x;
    const int lane = tid & 63;
    const int wid = tid >> 6;                    // 0..15
    const float* cb = coords + (size_t)b * 3 * N_;

    __shared__ float4 pts[N_];                   // 128 KiB
    __shared__ unsigned long long kbuf[2][16];

    float px[8], py[8], pz[8], mind[8];
#pragma unroll
    for (int s = 0; s < 8; ++s) {
        int p = tid + s * 1024;
        px[s] = cb[p];
        py[s] = cb[N_ + p];
        pz[s] = cb[2 * N_ + p];
        mind[s] = 1e10f;
        pts[p] = make_float4(px[s], py[s], pz[s], 0.f);
    }
    __syncthreads();
    float4 p0 = pts[0];
    float lx = p0.x, ly = p0.y, lz = p0.z;

    int w0 = 0, w1 = 0;                          // winner idx for m=tid, m=tid+1024
    int par = 0;
    for (int m = 1; m < M_; ++m) {
        float bv = -1.0f; int bi = 0;
#pragma unroll
        for (int s = 0; s < 8; ++s) {
            float dx = px[s] - lx;
            float dy = py[s] - ly;
            float dz = pz[s] - lz;
            float d = __builtin_fmaf(dz, dz, __builtin_fmaf(dy, dy, dx * dx));  // frozen
            float mn = fminf(mind[s], d);
            mind[s] = mn;
            if (mn > bv) { bv = mn; bi = tid + s * 1024; }   // strict >
        }
        unsigned kd = __float_as_uint(bv);
        unsigned md = wave_reduce_umax(kd);
        unsigned cand = (kd == md) ? (unsigned)bi : 0xffffffffu;
        unsigned mi = wave_reduce_umin(cand);
        if (lane == 0)
            kbuf[par][wid] = ((unsigned long long)md << 32) |
                             (unsigned long long)(0xffffffffu - mi);   // u64 max == lex rule
        __syncthreads();
        unsigned long long best = kbuf[par][0];
#pragma unroll
        for (int w = 1; w < 16; ++w) {
            unsigned long long k2 = kbuf[par][w];
            if (k2 > best) best = k2;
        }
        int widx = (int)(0xffffffffu - (unsigned)(best & 0xffffffffull));
        widx = ((unsigned)widx < (unsigned)N_) ? widx : 0;             // fault guard
        float4 wp = pts[widx];                                         // LDS broadcast
        lx = wp.x; ly = wp.y; lz = wp.z;
        if (m == tid) w0 = widx;
        if (m == tid + 1024) w1 = widx;
        par ^= 1;
    }

    // epilogue: write fpts + out_fps (2 winners per thread, m=0 by thread 0)
    if (tid == 0) {
        ((float4*)fpts)[b * M_ + 0] = make_float4(p0.x, p0.y, p0.z, 0.f);
        out_fps[(size_t)b * 3 * M_ + 0 * M_ + 0] = p0.x;
        out_fps[(size_t)b * 3 * M_ + 1 * M_ + 0] = p0.y;
        out_fps[(size_t)b * 3 * M_ + 2 * M_ + 0] = p0.z;
    }
    if (tid >= 1) {
        float4 wp = pts[w0];
        ((float4*)fpts)[b * M_ + tid] = make_float4(wp.x, wp.y, wp.z, 0.f);
        out_fps[(size_t)b * 3 * M_ + 0 * M_ + tid] = wp.x;
        out_fps[(size_t)b * 3 * M_ + 1 * M_ + tid] = wp.y;
        out_fps[(size_t)b * 3 * M_ + 2 * M_ + tid] = wp.z;
    }
    {
        int m = tid + 1024;
        float4 wp = pts[w1];
        ((float4*)fpts)[b * M_ + m] = make_float4(wp.x, wp.y, wp.z, 0.f);
        out_fps[(size_t)b * 3 * M_ + 0 * M_ + m] = wp.x;
        out_fps[(size_t)b * 3 * M_ + 1 * M_ + m] = wp.y;
        out_fps[(size_t)b * 3 * M_ + 2 * M_ + m] = wp.z;
    }
}

// ---------------------------------------------------------------------------
// kNN: ONE WAVE per (b,m) row (R1 structure — empirically bit-equivalent to
// brute force via R1==R3 output equality). Top-16 as lane-distributed sorted
// list (lane r = rank r, lanes 16..63 sentinels); fast path = dist + 1 ballot
// per 64 candidates; inserts are wave-uniform shuffles. Distances use the
// FROZEN fmaf op order; sp staged once per block (per-point, row-independent).
// ---------------------------------------------------------------------------
__global__ __launch_bounds__(256) void knn_kernel(const float* __restrict__ coords,
                                                  const float* __restrict__ fpts,
                                                  int* __restrict__ knn) {
#pragma clang fp contract(off)
    const int bidx = blockIdx.x;
    const int b = bidx >> 9;                  // 512 blocks per batch
    const int mg = bidx & 511;
    const int tid = threadIdx.x;
    const int lane = tid & 63;
    const int w = tid >> 6;
    const int m = mg * 4 + w;
    const int row = b * M_ + m;
    const float* cb = coords + (size_t)b * 3 * N_;

    __shared__ float4 tile[1024];

    float4 f = ((const float4*)fpts)[row];
    const float fx = f.x, fy = f.y, fz = f.z;
    const float sf = __builtin_fmaf(fz, fz, __builtin_fmaf(fy, fy, fx * fx));  // frozen

    float ed = INFINITY; int ei = 0x7fffffff;     // distributed list entry
    float tau_d = INFINITY; int tau_i = 0x7fffffff;

    for (int t = 0; t < 8; ++t) {
        const int base = t * 1024;
#pragma unroll
        for (int j = 0; j < 4; ++j) {
            int idx = tid + 256 * j;
            int n = base + idx;
            float gx = cb[n], gy = cb[N_ + n], gz = cb[2 * N_ + n];
            float sp = __builtin_fmaf(gz, gz, __builtin_fmaf(gy, gy, gx * gx)); // frozen
            tile[idx] = make_float4(gx, gy, gz, sp);
        }
        __syncthreads();
        for (int s = 0; s < 16; ++s) {
            int l = s * 64 + lane;
            float4 p = tile[l];
            int n = base + l;
            float dot = __builtin_fmaf(fz, p.z, __builtin_fmaf(fy, p.y, fx * p.x)); // frozen
            float d = (sf + p.w) - 2.0f * dot;                                      // frozen
            bool q = (d < tau_d) || (d == tau_d && n < tau_i);
            unsigned long long bal = __ballot(q);
            while (bal) {
                int lb = __ffsll(bal) - 1;
                bal &= bal - 1;
                float dv = __shfl(d, lb);
                int   iv = __shfl(n, lb);
                if ((dv < tau_d) || (dv == tau_d && iv < tau_i)) {
                    float pud = __shfl_up(ed, 1);
                    int   pui = __shfl_up(ei, 1);
                    bool cs = (dv < ed) || (dv == ed && iv < ei);
                    bool cp = (lane != 0) && ((dv < pud) || (dv == pud && iv < pui));
                    ed = cs ? (cp ? pud : dv) : ed;
                    ei = cs ? (cp ? pui : iv) : ei;
                    tau_d = __shfl(ed, 15);
                    tau_i = __shfl(ei, 15);
                }
            }
        }
        __syncthreads();
    }
    if (lane < K_) {
        int v = ei;
        knn[(size_t)row * K_ + lane] = ((unsigned)v < (unsigned)N_) ? v : 0;  // fault guard
    }
}

// ---------------------------------------------------------------------------
// Per-point GEMM: hp[b][n][o] = sum_c x[b][c][n] * W[o][c]  (unchanged)
// ---------------------------------------------------------------------------
__global__ __launch_bounds__(256) void gemm_kernel(const float* __restrict__ x,
                                                   const float* __restrict__ W,
                                                   float* __restrict__ hp) {
    const int bid = blockIdx.x;
    const int b = bid >> 9;
    const int rem = bid & 511;
    const int n0 = (rem >> 2) * 64;
    const int o0 = (rem & 3) * 64;
    const int tid = threadIdx.x;
    const int tn = (tid & 15) * 4;
    const int to = (tid >> 4) * 4;
    const float* xg = x + (size_t)b * CIN_ * N_;

    __shared__ float Xs[64][64];
    __shared__ float Wt[64][68];

    float acc[4][4] = {};
    for (int kk = 0; kk < CIN_; kk += 64) {
#pragma unroll
        for (int i = 0; i < 16; ++i) {
            int e = tid + 256 * i;
            int r = e >> 6, q = e & 63;
            Xs[r][q] = xg[(size_t)(kk + r) * N_ + n0 + q];
            Wt[q][r] = W[(size_t)(o0 + r) * CIN_ + kk + q];
        }
        __syncthreads();
#pragma unroll 8
        for (int c = 0; c < 64; ++c) {
            float4 a = *(const float4*)&Xs[c][tn];
            float4 bb = *(const float4*)&Wt[c][to];
            float av[4] = {a.x, a.y, a.z, a.w};
            float bv[4] = {bb.x, bb.y, bb.z, bb.w};
#pragma unroll
            for (int j = 0; j < 4; ++j)
#pragma unroll
                for (int l = 0; l < 4; ++l)
                    acc[j][l] += av[j] * bv[l];
        }
        __syncthreads();
    }
#pragma unroll
    for (int j = 0; j < 4; ++j) {
        float4 v = make_float4(acc[j][0], acc[j][1], acc[j][2], acc[j][3]);
        *(float4*)&hp[((size_t)b * N_ + n0 + tn + j) * COUT_ + o0 + to] = v;
    }
}

// ---------------------------------------------------------------------------
// BN stats stage 1: deterministic per-block f64 partials (unchanged).
// ---------------------------------------------------------------------------
__global__ __launch_bounds__(256) void stats_partial_kernel(const float* __restrict__ hp,
                                                            const int* __restrict__ knn,
                                                            double* __restrict__ partial,
                                                            double* __restrict__ partial2) {
    const int o = threadIdx.x;
    const int g0 = blockIdx.x * 1024;              // 262144 gathered rows total
    double s = 0.0, s2 = 0.0;
    for (int r = 0; r < 1024; ++r) {
        int g = g0 + r;                            // g = (b*M + m)*K + k
        int row = g >> 4;
        int k = g & 15;
        int b = row >> 11;
        int n = knn[row * K_ + k];
        n = ((unsigned)n < (unsigned)N_) ? n : 0;  // fault guard
        double h = (double)hp[((size_t)b * N_ + n) * COUT_ + o];
        s += h;
        s2 += h * h;
    }
    partial[(size_t)blockIdx.x * 256 + o] = s;
    partial2[(size_t)blockIdx.x * 256 + o] = s2;
}

__global__ void bn_final_kernel(const double* __restrict__ partial,
                                const double* __restrict__ partial2,
                                const float* __restrict__ gamma,
                                const float* __restrict__ beta,
                                float* __restrict__ scale,
                                float* __restrict__ bias) {
    int o = threadIdx.x;
    double s = 0.0, s2 = 0.0;
    for (int j = 0; j < 256; ++j) {
        s += partial[(size_t)j * 256 + o];
        s2 += partial2[(size_t)j * 256 + o];
    }
    const double inv = 1.0 / (double)(B_ * M_ * K_);
    double mean = s * inv;
    double var = s2 * inv - mean * mean;
    if (var < 0.0) var = 0.0;
    double r = 1.0 / sqrt(var + 1e-5);
    double g = (double)gamma[o];
    scale[o] = (float)(r * g);
    bias[o] = (float)((double)beta[o] - mean * r * g);
}

// ---------------------------------------------------------------------------
// Finalize: y[b][o][m] = relu( max_k ( hp[gather] * scale + bias ) ) (unchanged)
// ---------------------------------------------------------------------------
__global__ __launch_bounds__(256) void finalize_kernel(const float* __restrict__ hp,
                                                       const int* __restrict__ knn,
                                                       const float* __restrict__ scale,
                                                       const float* __restrict__ bias,
                                                       float* __restrict__ y) {
    const int b = blockIdx.x >> 6;
    const int m0 = (blockIdx.x & 63) * 32;
    const int tid = threadIdx.x;
    __shared__ int kidx[512];
    __shared__ float tile[32][257];

    for (int e = tid; e < 512; e += 256) {
        int n = knn[(b * M_ + m0 + (e >> 4)) * K_ + (e & 15)];
        kidx[e] = ((unsigned)n < (unsigned)N_) ? n : 0;   // fault guard
    }
    __syncthreads();

    const float s = scale[tid];
    const float t = bias[tid];
    const float* hb = hp + (size_t)b * N_ * COUT_;
    for (int mm = 0; mm < 32; ++mm) {
        float v = -INFINITY;
#pragma unroll
        for (int k = 0; k < K_; ++k) {
            int n = kidx[mm * 16 + k];
            float h = hb[(size_t)n * COUT_ + tid];
            v = fmaxf(v, h * s + t);
        }
        v = fmaxf(v, 0.0f);
        tile[mm][tid] = v;
    }
    __syncthreads();
#pragma unroll
    for (int r = 0; r < 32; ++r) {
        int o2 = r * 8 + (tid >> 5);
        int mm = tid & 31;
        y[((size_t)b * COUT_ + o2) * M_ + m0 + mm] = tile[mm][o2];
    }
}

__global__ void sentinel_kernel(float* out, float v) { out[0] = v; }

// ---------------------------------------------------------------------------
extern "C" void kernel_launch(void* const* d_in, const int* in_sizes, int n_in,
                              void* d_out, int out_size, void* d_ws, size_t ws_size,
                              hipStream_t stream) {
    const float* x = (const float*)d_in[0];
    const float* coords = (const float*)d_in[1];
    const float* W = (const float*)d_in[2];
    const float* gamma = (const float*)d_in[3];
    const float* beta = (const float*)d_in[4];
    float* y = (float*)d_out;
    float* out_fps = y + (size_t)B_ * COUT_ * M_;     // fps_coords after y (f32)

    if (n_in != 5 ||
        in_sizes[0] != B_ * CIN_ * N_ ||
        in_sizes[1] != B_ * 3 * N_ ||
        in_sizes[2] != COUT_ * CIN_ ||
        in_sizes[3] != COUT_ || in_sizes[4] != COUT_ ||
        out_size != B_ * COUT_ * M_ + B_ * 3 * M_) {
        sentinel_kernel<<<1, 1, 0, stream>>>(y, -2.0e6f);
        return;
    }

    const size_t HP_BYTES = (size_t)B_ * N_ * COUT_ * 4;          // 64 MB
    const size_t FPTS_BYTES = (size_t)B_ * M_ * 16;               // 256 KB
    const size_t KNN_BYTES = (size_t)B_ * M_ * K_ * 4;            // 1 MB
    const size_t PART_BYTES = (size_t)256 * 256 * 8;              // 512 KB
    const size_t NEED = HP_BYTES + FPTS_BYTES + KNN_BYTES + 2 * PART_BYTES + 8192;
    if (ws_size < NEED) {
        sentinel_kernel<<<1, 1, 0, stream>>>(y, -1.0e6f);
        return;
    }
    char* ws = (char*)d_ws;
    float* hp = (float*)ws;
    float* fpts = (float*)(ws + HP_BYTES);
    int* knn = (int*)(ws + HP_BYTES + FPTS_BYTES);
    double* partial = (double*)(ws + HP_BYTES + FPTS_BYTES + KNN_BYTES);
    double* partial2 = (double*)(ws + HP_BYTES + FPTS_BYTES + KNN_BYTES + PART_BYTES);
    float* scale = (float*)(ws + HP_BYTES + FPTS_BYTES + KNN_BYTES + 2 * PART_BYTES);
    float* bias = scale + 256;

    fps_kernel<<<B_, 1024, 0, stream>>>(coords, fpts, out_fps);
    knn_kernel<<<B_ * 512, 256, 0, stream>>>(coords, fpts, knn);
    gemm_kernel<<<B_ * 512, 256, 0, stream>>>(x, W, hp);
    stats_partial_kernel<<<256, 256, 0, stream>>>(hp, knn, partial, partial2);
    bn_final_kernel<<<1, 256, 0, stream>>>(partial, partial2, gamma, beta, scale, bias);
    finalize_kernel<<<512, 256, 0, stream>>>(hp, knn, scale, bias, y);
}